// Round 15
// baseline (95.921 us; speedup 1.0000x reference)
//
#include <hip/hip_runtime.h>

typedef unsigned long long u64;
typedef unsigned int u32;

#define N1 4096
#define N2 2048
#define NT 6144
#define CAP 4096
#define MCAP 4096
#define IMG 1280.0f
#define MATCH_IOU_T 0.8f
#define NMS_IOU_T 0.95f
#define NRANKBLK (NT / 16)

// IoU with exact op-order mirroring of the reference (no FMA contraction).
__device__ __forceinline__ float iou_f(const float* a, const float* b) {
    float x1 = fmaxf(a[0], b[0]);
    float y1 = fmaxf(a[1], b[1]);
    float x2 = fminf(a[2], b[2]);
    float y2 = fminf(a[3], b[3]);
    float dx = fmaxf(__fsub_rn(x2, x1), 0.0f);
    float dy = fmaxf(__fsub_rn(y2, y1), 0.0f);
    float inter = __fmul_rn(dx, dy);
    float a1 = __fmul_rn(__fsub_rn(a[2], a[0]), __fsub_rn(a[3], a[1]));
    float a2 = __fmul_rn(__fsub_rn(b[2], b[0]), __fsub_rn(b[3], b[1]));
    float den = __fsub_rn(__fadd_rn(a1, a2), inter);
    return __fdiv_rn(inter, den);
}

__device__ __forceinline__ u64 make_key(float f, int idx) {
    u32 u = __float_as_uint(f);
    u32 asc = (u >> 31) ? ~u : (u | 0x80000000u);
    return (((u64)(~asc)) << 32) | (u32)idx;
}

// kX: ONE yolo row per block (wide grid). Emit all match candidate pairs
// (same label, unmasked IoU >= 0.8) with exact IoU.
__global__ void __launch_bounds__(256) kX(const float* yb, const int* yl,
                                          const int* fl, const float* fb,
                                          int* mpcount, u64* mpk, float* mpi) {
    int i = blockIdx.x;
    int tid = threadIdx.x;
    float a[4];
#pragma unroll
    for (int c = 0; c < 4; c++) a[c] = __fdiv_rn(yb[i * 4 + c], IMG);
    int lab = yl[i];
    for (int j = tid; j < N2; j += 256) {
        if (fl[j] == lab) {
            float bb[4];
#pragma unroll
            for (int c = 0; c < 4; c++) bb[c] = __fdiv_rn(fb[j * 4 + c], IMG);
            float v = iou_f(a, bb);
            if (v >= MATCH_IOU_T) {
                int pos = atomicAdd(mpcount, 1);
                if (pos < MCAP) { mpk[pos] = (((u64)(u32)i) << 32) | (u32)j; mpi[pos] = v; }
            }
        }
    }
}

// k2: single block. Sort pairs by (i<<32)|j (argmax lowest-j semantics),
// thread-0 greedy walk, then write FINAL normalized boxes sball / scores
// sall / valid vall / sort keys for all 6144 rows (defaults + merge patch).
__global__ void __launch_bounds__(256) k2(const float* yb, const float* ys,
                                          const float* fb, const float* fs,
                                          const int* mpcount, const u64* mpk,
                                          const float* mpi,
                                          float* sball, float* sall, int* vall,
                                          u64* keys) {
    __shared__ u64 pk[MCAP];            // 32 KB
    __shared__ float pv[MCAP];          // 16 KB
    __shared__ unsigned char dec[MCAP]; //  4 KB
    __shared__ unsigned char used[N2];  //  2 KB
    int tid = threadIdx.x;
    int np = *mpcount;
    if (np > MCAP) np = MCAP;
    for (int t = tid; t < MCAP; t += 256) {
        pk[t] = (t < np) ? mpk[t] : ~0ULL;
        pv[t] = (t < np) ? mpi[t] : 0.0f;
        dec[t] = 0;
    }
    for (int j = tid; j < N2; j += 256) used[j] = 0;
    __syncthreads();
    if (np > 0) {
        int m = 2;
        while (m < np) m <<= 1;
        for (int k2v = 2; k2v <= m; k2v <<= 1) {
            for (int jj = k2v >> 1; jj > 0; jj >>= 1) {
                for (int idx = tid; idx < m; idx += 256) {
                    int l = idx ^ jj;
                    if (l > idx) {
                        u64 A = pk[idx], B = pk[l];
                        bool up = ((idx & k2v) == 0);
                        if (up ? (A > B) : (A < B)) {
                            pk[idx] = B; pk[l] = A;
                            float fA = pv[idx]; pv[idx] = pv[l]; pv[l] = fA;
                        }
                    }
                }
                __syncthreads();
            }
        }
        if (tid == 0) {
            int cur_i = -1, best_p = -1, best_j = -1;
            float best_v = -1.0f;
            for (int p = 0; p < np; p++) {
                u64 pr = pk[p];
                int i = (int)(pr >> 32);
                int j = (int)(pr & 0xffffffffu);
                if (i != cur_i) {
                    if (best_p >= 0) { dec[best_p] = 1; used[best_j] = 1; }
                    cur_i = i; best_p = -1; best_j = -1; best_v = -1.0f;
                }
                if (!used[j]) {
                    float v = pv[p];
                    if (v > best_v) { best_v = v; best_p = p; best_j = j; }
                }
            }
            if (best_p >= 0) { dec[best_p] = 1; used[best_j] = 1; }
        }
        __syncthreads();
    }
    // defaults for all rows (normalized boxes, weighted scores, valid)
    for (int idx = tid; idx < NT; idx += 256) {
        if (idx < N1) {
#pragma unroll
            for (int c = 0; c < 4; c++) sball[idx * 4 + c] = __fdiv_rn(yb[idx * 4 + c], IMG);
            sall[idx] = __fmul_rn(ys[idx], 0.5f);
            vall[idx] = 1;
        } else {
            int j = idx - N1;
#pragma unroll
            for (int c = 0; c < 4; c++) sball[idx * 4 + c] = __fdiv_rn(fb[j * 4 + c], IMG);
            sall[idx] = __fmul_rn(fs[j], 0.5f);
            vall[idx] = used[j] ? 0 : 1;
        }
    }
    __syncthreads();
    // merge patch (one dec'd pair per i -> disjoint; reads defaults just written)
    for (int p = tid; p < np; p += 256) {
        if (dec[p]) {
            u64 pr = pk[p];
            int i = (int)(pr >> 32);
            int j = (int)(pr & 0xffffffffu);
            float s2 = __fmul_rn(fs[j], 0.5f);
            float sc0 = sall[i];
            float tot = __fadd_rn(sc0, s2);
#pragma unroll
            for (int cc = 0; cc < 4; cc++) {
                float b2v = __fdiv_rn(fb[j * 4 + cc], IMG);
                float merged = __fdiv_rn(
                    __fadd_rn(__fmul_rn(sball[i * 4 + cc], sc0),
                              __fmul_rn(b2v, s2)), tot);
                sball[i * 4 + cc] = merged;
            }
            sall[i] = tot;
        }
    }
    __syncthreads();
    // keys from final scores
    for (int idx = tid; idx < NT; idx += 256)
        keys[idx] = make_key(vall[idx] ? sall[idx] : -1.0f, idx);
}

// kYZ: one grid, two independent roles (both depend only on k2 outputs).
// blocks [0,384): rank-count 16 rows each + gather boxes/labels/scores to
//   output + write ord[rank]=id (ranks unique -> disjoint).
// blocks [384,384+NT): NMS-pair detection for unsorted row a: triangle b>a,
//   same label, both valid, IoU >= 0.95; orientation by key order (rank
//   order == key order); append 128-bit (key_first, key_second).
__global__ void __launch_bounds__(256) kYZ(const u64* keys, const float* sball,
                                           const float* sall, const int* vall,
                                           const int* yl, const int* fl,
                                           int* ord, float* out,
                                           int* pcount, u64* phi, u64* plo) {
    int tid = threadIdx.x;
    if (blockIdx.x < NRANKBLK) {
        __shared__ int cnts[16];
        if (tid < 16) cnts[tid] = 0;
        __syncthreads();
        int i0 = blockIdx.x * 16;
        u64 myk[16];
#pragma unroll
        for (int g = 0; g < 16; g++) myk[g] = keys[i0 + g];
        int local[16];
#pragma unroll
        for (int g = 0; g < 16; g++) local[g] = 0;
        for (int j = tid; j < NT; j += 256) {
            u64 kj = keys[j];
#pragma unroll
            for (int g = 0; g < 16; g++) local[g] += (kj < myk[g]) ? 1 : 0;
        }
#pragma unroll
        for (int g = 0; g < 16; g++) {
            int v = local[g];
#pragma unroll
            for (int s = 32; s > 0; s >>= 1) v += __shfl_down(v, s, 64);
            if ((tid & 63) == 0) atomicAdd(&cnts[g], v);
        }
        __syncthreads();
        if (tid < 16) {
            int i = i0 + tid;
            int r = cnts[tid];
            int lab = (i < N1) ? yl[i] : fl[i - N1];
#pragma unroll
            for (int c = 0; c < 4; c++)
                out[r * 4 + c] = __fmul_rn(sball[i * 4 + c], IMG);
            out[24576 + r] = (lab == 0) ? 2.0f : 1.0f;   // label_map
            out[24576 + NT + r] = sall[i];                // sorted scores
            ord[r] = i;
        }
    } else {
        int a = blockIdx.x - NRANKBLK;
        if (!vall[a]) return;   // invalid rows never produce effective pairs
        float bx[4] = {sball[a * 4], sball[a * 4 + 1], sball[a * 4 + 2], sball[a * 4 + 3]};
        int lab = (a < N1) ? yl[a] : fl[a - N1];
        u64 ka = keys[a];
        for (int b = a + 1 + tid; b < NT; b += 256) {
            int labb = (b < N1) ? yl[b] : fl[b - N1];
            if (labb == lab && vall[b]) {
                float bb[4] = {sball[b * 4], sball[b * 4 + 1], sball[b * 4 + 2], sball[b * 4 + 3]};
                if (iou_f(bx, bb) >= NMS_IOU_T) {
                    u64 kb = keys[b];
                    int pos = atomicAdd(pcount, 1);
                    if (pos < CAP) {
                        if (ka < kb) { phi[pos] = ka; plo[pos] = kb; }
                        else         { phi[pos] = kb; plo[pos] = ka; }
                    }
                }
            }
        }
    }
}

// kW: single block. 128-bit bitonic sort of pairs by (hi,lo) == (rank_a,
// rank_b) ascending == exact reference walk order; serial suppression over
// unsorted ids; keep mask written by rank via ord.
__global__ void __launch_bounds__(256) kW(const int* pcount, const u64* phi,
                                          const u64* plo, const int* vall,
                                          const int* ord, float* out) {
    __shared__ u64 hi[CAP];            // 32 KB
    __shared__ u64 lo[CAP];            // 32 KB
    __shared__ unsigned char sup[NT];  //  6 KB
    int tid = threadIdx.x;
    int np = *pcount;
    if (np > CAP) np = CAP;
    int m = 2;
    while (m < np) m <<= 1;   // block-uniform
    for (int t = tid; t < m; t += 256) {
        hi[t] = (t < np) ? phi[t] : ~0ULL;
        lo[t] = (t < np) ? plo[t] : ~0ULL;
    }
    for (int k = tid; k < NT; k += 256) sup[k] = vall[k] ? 0 : 1;
    __syncthreads();
    if (np > 0) {
        for (int k2v = 2; k2v <= m; k2v <<= 1) {
            for (int jj = k2v >> 1; jj > 0; jj >>= 1) {
                for (int idx = tid; idx < m; idx += 256) {
                    int l = idx ^ jj;
                    if (l > idx) {
                        u64 Ah = hi[idx], Al = lo[idx];
                        u64 Bh = hi[l],   Bl = lo[l];
                        bool up = ((idx & k2v) == 0);
                        bool agtb = (Ah > Bh) || (Ah == Bh && Al > Bl);
                        if (up ? agtb : !agtb && !(Ah == Bh && Al == Bl)) {
                            hi[idx] = Bh; lo[idx] = Bl;
                            hi[l] = Ah; lo[l] = Al;
                        }
                    }
                }
                __syncthreads();
            }
        }
        if (tid == 0) {
            for (int p = 0; p < np; p++) {
                int ia = (int)(u32)hi[p];   // key low 32 bits = unsorted id
                int ib = (int)(u32)lo[p];
                if (!sup[ia]) sup[ib] = 1;
            }
        }
        __syncthreads();
    }
    for (int r = tid; r < NT; r += 256)
        out[24576 + 2 * NT + r] = sup[ord[r]] ? 0.0f : 1.0f;
}

extern "C" void kernel_launch(void* const* d_in, const int* in_sizes, int n_in,
                              void* d_out, int out_size, void* d_ws, size_t ws_size,
                              hipStream_t stream) {
    const float* yb = (const float*)d_in[0];
    const float* ys = (const float*)d_in[1];
    const int*   yl = (const int*)d_in[2];
    const float* fb = (const float*)d_in[3];
    const float* fs = (const float*)d_in[4];
    const int*   fl = (const int*)d_in[5];
    float* out = (float*)d_out;
    char* ws = (char*)d_ws;

    float* sball   = (float*)(ws);            // 6144*4 f = 98304 B
    float* sall    = (float*)(ws + 98304);    // 6144 f   = 24576 B
    int*   vall    = (int*)  (ws + 122880);   // 6144 i   = 24576 B
    u64*   keys    = (u64*)  (ws + 147456);   // 6144 u64 = 49152 B
    int*   ord     = (int*)  (ws + 196608);   // 6144 i   = 24576 B
    int*   cnt     = (int*)  (ws + 221184);   // 2 ints: pcount, mpcount
    u64*   mpk     = (u64*)  (ws + 221200);   // 4096 u64 = 32768 B
    float* mpi     = (float*)(ws + 253968);   // 4096 f   = 16384 B
    u64*   phi     = (u64*)  (ws + 270352);   // 4096 u64 = 32768 B
    u64*   plo     = (u64*)  (ws + 303120);   // 4096 u64 = 32768 B (end ~336 KB)
    int* pcount  = cnt + 0;
    int* mpcount = cnt + 1;

    hipMemsetAsync(cnt, 0, 8, stream);
    hipLaunchKernelGGL(kX,  dim3(N1),            dim3(256), 0, stream,
                       yb, yl, fl, fb, mpcount, mpk, mpi);
    hipLaunchKernelGGL(k2,  dim3(1),             dim3(256), 0, stream,
                       yb, ys, fb, fs, mpcount, mpk, mpi, sball, sall, vall, keys);
    hipLaunchKernelGGL(kYZ, dim3(NRANKBLK + NT), dim3(256), 0, stream,
                       keys, sball, sall, vall, yl, fl, ord, out, pcount, phi, plo);
    hipLaunchKernelGGL(kW,  dim3(1),             dim3(256), 0, stream,
                       pcount, phi, plo, vall, ord, out);
}